// Round 6
// baseline (1260.905 us; speedup 1.0000x reference)
//
#include <hip/hip_runtime.h>
#include <hip/hip_bf16.h>
#include <hip/hip_fp16.h>

// SimpleRNN: B=64, S=2048, IN=256, H=128, OUT=3 (all fp32)
// Phase 1: xproj MFMA GEMM (byte-identical to r14; stores xp as [t][b][h]).
// Phase 2 (r15): operand-SWAPPED MFMA scan. r14's counters showed 1.05M LDS
//   bank conflicts (4x scattered ds_write_b16 C/D stores) + a 32 KB/step LDS
//   read floor (8 waves x full h-tile). Now D[col][batch] = W x h^T:
//   per lane D = (batch fr, 4 contiguous cols) -> ONE ds_write_b64, and the
//   xp C-in is ONE global dwordx4. 4 waves x 2 col-tiles/wave: B-frags (h)
//   are tile-independent -> h-tile read once per wave = 16 KB/step (halved),
//   4-wave barrier. Weights: 8 x half8 = 32 persistent VGPR (between the
//   proven-good 16 and the spill-failing 64+), launch_bounds(256,1).

#define RNN_B   64
#define RNN_S   2048
#define RNN_IN  256
#define RNN_H   128
#define RNN_OUT 3

typedef _Float16 half2v __attribute__((ext_vector_type(2)));
typedef _Float16 half4 __attribute__((ext_vector_type(4)));
typedef _Float16 half8 __attribute__((ext_vector_type(8)));
typedef float f32x4 __attribute__((ext_vector_type(4)));

// LDS-only barrier: drains lgkm (LDS) but NOT vmcnt, so global prefetch
// loads stay in flight across the barrier.
__device__ __forceinline__ void block_sync_lds() {
  asm volatile("s_waitcnt lgkmcnt(0)" ::: "memory");
  __builtin_amdgcn_s_barrier();
}

// ---------------------------------------------------------------------------
// Phase 1: f16 MFMA GEMM  C[M=131072, N=128] = A[M,256] * B[128,256]^T + bias
// (byte-identical to round 5 for attribution; epilogue stores xp[t][b][h])
// ---------------------------------------------------------------------------
#define XLOADC(SET, KC)                                                       \
  {                                                                           \
    const int _kc = (KC);                                                     \
    _Pragma("unroll")                                                         \
    for (int p = 0; p < 4; ++p) {                                             \
      const int row = lr + 32 * p;                                            \
      SET##a[p] = *(const float4*)&x[(size_t)(m0 + row) * RNN_IN + _kc + lc]; \
      SET##b[p] = *(const float4*)&Wxh[(size_t)row * RNN_IN + _kc + lc];      \
    }                                                                         \
  }

#define XSTORE(SET)                                                 \
  {                                                                 \
    _Pragma("unroll")                                               \
    for (int p = 0; p < 4; ++p) {                                   \
      const int row = lr + 32 * p;                                  \
      half4 ha, hb;                                                 \
      ha.x = (_Float16)SET##a[p].x; ha.y = (_Float16)SET##a[p].y;   \
      ha.z = (_Float16)SET##a[p].z; ha.w = (_Float16)SET##a[p].w;   \
      hb.x = (_Float16)SET##b[p].x; hb.y = (_Float16)SET##b[p].y;   \
      hb.z = (_Float16)SET##b[p].z; hb.w = (_Float16)SET##b[p].w;   \
      *(half4*)&Ash[row][lc] = ha;                                  \
      *(half4*)&Bsh[row][lc] = hb;                                  \
    }                                                               \
  }

#define XCOMPUTE()                                                  \
  {                                                                 \
    half8 af[4], bf[4];                                             \
    _Pragma("unroll")                                               \
    for (int m = 0; m < 4; ++m)                                     \
      af[m] = *(const half8*)&Ash[wr * 64 + m * 16 + fr][fk * 8];   \
    _Pragma("unroll")                                               \
    for (int n = 0; n < 4; ++n)                                     \
      bf[n] = *(const half8*)&Bsh[wc * 64 + n * 16 + fr][fk * 8];   \
    _Pragma("unroll")                                               \
    for (int m = 0; m < 4; ++m)                                     \
      _Pragma("unroll")                                             \
      for (int n = 0; n < 4; ++n)                                   \
        acc[m][n] = __builtin_amdgcn_mfma_f32_16x16x32_f16(         \
            af[m], bf[n], acc[m][n], 0, 0, 0);                      \
  }

__global__ __launch_bounds__(256, 2) void xproj_mfma(
    const float* __restrict__ x, const float* __restrict__ Wxh,
    const float* __restrict__ bxh, float* __restrict__ xp) {
  __shared__ __align__(16) _Float16 Ash[128][40];
  __shared__ __align__(16) _Float16 Bsh[128][40];

  const int tid = threadIdx.x;
  const int m0 = blockIdx.x * 128;
  const int wv = tid >> 6;
  const int lane = tid & 63;
  const int wr = wv >> 1;
  const int wc = wv & 1;
  const int fr = lane & 15;
  const int fk = lane >> 4;

  const int lr = tid >> 3;
  const int lc = (tid & 7) * 4;

  f32x4 acc[4][4];
#pragma unroll
  for (int m = 0; m < 4; ++m)
#pragma unroll
    for (int n = 0; n < 4; ++n) {
      acc[m][n][0] = 0.f; acc[m][n][1] = 0.f;
      acc[m][n][2] = 0.f; acc[m][n][3] = 0.f;
    }

  float4 Aa[4], Ab[4], Ba[4], Bb[4];
  XLOADC(A, 0)

#pragma unroll 1
  for (int kc = 0; kc < RNN_IN; kc += 64) {
    XSTORE(A)
    { const int nk = kc + 32; XLOADC(B, nk < RNN_IN ? nk : RNN_IN - 32) }
    block_sync_lds();
    XCOMPUTE()
    block_sync_lds();
    XSTORE(B)
    { const int nk = kc + 64; XLOADC(A, nk < RNN_IN ? nk : RNN_IN - 32) }
    block_sync_lds();
    XCOMPUTE()
    block_sync_lds();
  }

  float bb[4];
#pragma unroll
  for (int n = 0; n < 4; ++n) bb[n] = bxh[wc * 64 + n * 16 + fr];
#pragma unroll
  for (int m = 0; m < 4; ++m) {
    const size_t rbase = (size_t)(m0 + wr * 64 + m * 16 + 4 * fk);
#pragma unroll
    for (int reg = 0; reg < 4; ++reg) {
      const size_t grow = rbase + reg;            // global row = b*2048 + t
      const size_t bidx = grow >> 11;             // batch
      const size_t tidx = grow & 2047;            // timestep
      float* rowp = &xp[(tidx * RNN_B + bidx) * RNN_H];
#pragma unroll
      for (int n = 0; n < 4; ++n)
        rowp[wc * 64 + n * 16 + fr] = acc[m][n][reg] + bb[n];
    }
  }
}

// fast tanh: 1 - 2/(exp(2x)+1); saturates correctly at +-inf
__device__ __forceinline__ float fast_tanh(float a) {
  const float e = __expf(2.f * a);
  return 1.f - 2.f / (e + 1.f);
}

// ---------------------------------------------------------------------------
// Phase 2: operand-swapped MFMA scan. grid = 4 blocks x 256 thr (4 waves).
// Wave w owns col-tiles cb0=32w, cb1=32w+16 (A = W_hh rows = output cols).
// D[m=col][n=batch]: lane (fr,fk) -> batch fr, cols cb+4fk..+3 (contiguous).
// h LDS rows (batch) are 256 B, element (bb,cc) at byte (bb*256+2cc)^((bb&7)<<4).
// ---------------------------------------------------------------------------

// load both tiles' xp C-in fragments for step T (one dwordx4 each)
#define LDPX(PA, PB, T)                                               \
  {                                                                   \
    const size_t _o = (size_t)(T) * (RNN_B * RNN_H);                  \
    PA = *(const float4*)(xb0 + _o);                                  \
    PB = *(const float4*)(xb1 + _o);                                  \
  }

#define SSTEP(CUR, NXT, PA, PB, TNEXT)                                 \
  {                                                                    \
    const char* hb = &hls[CUR][0];                                     \
    const half8 h0 = *(const half8*)(hb + r0);                         \
    const half8 h1 = *(const half8*)(hb + r1);                         \
    const half8 h2 = *(const half8*)(hb + r2);                         \
    const half8 h3 = *(const half8*)(hb + r3);                         \
    f32x4 acc0, acc1;                                                  \
    acc0[0] = PA.x; acc0[1] = PA.y; acc0[2] = PA.z; acc0[3] = PA.w;    \
    acc1[0] = PB.x; acc1[1] = PB.y; acc1[2] = PB.z; acc1[3] = PB.w;    \
    LDPX(PA, PB, TNEXT)                                                \
    acc0 = __builtin_amdgcn_mfma_f32_16x16x32_f16(w0c0, h0, acc0, 0,0,0); \
    acc1 = __builtin_amdgcn_mfma_f32_16x16x32_f16(w1c0, h0, acc1, 0,0,0); \
    acc0 = __builtin_amdgcn_mfma_f32_16x16x32_f16(w0c1, h1, acc0, 0,0,0); \
    acc1 = __builtin_amdgcn_mfma_f32_16x16x32_f16(w1c1, h1, acc1, 0,0,0); \
    acc0 = __builtin_amdgcn_mfma_f32_16x16x32_f16(w0c2, h2, acc0, 0,0,0); \
    acc1 = __builtin_amdgcn_mfma_f32_16x16x32_f16(w1c2, h2, acc1, 0,0,0); \
    acc0 = __builtin_amdgcn_mfma_f32_16x16x32_f16(w0c3, h3, acc0, 0,0,0); \
    acc1 = __builtin_amdgcn_mfma_f32_16x16x32_f16(w1c3, h3, acc1, 0,0,0); \
    hvA.x = fast_tanh(acc0[0] + bias0.x);                              \
    hvA.y = fast_tanh(acc0[1] + bias0.y);                              \
    hvA.z = fast_tanh(acc0[2] + bias0.z);                              \
    hvA.w = fast_tanh(acc0[3] + bias0.w);                              \
    hvB.x = fast_tanh(acc1[0] + bias1.x);                              \
    hvB.y = fast_tanh(acc1[1] + bias1.y);                              \
    hvB.z = fast_tanh(acc1[2] + bias1.z);                              \
    hvB.w = fast_tanh(acc1[3] + bias1.w);                              \
    char* hn = &hls[NXT][0];                                           \
    half4 pk0, pk1;                                                    \
    pk0.x = (_Float16)hvA.x; pk0.y = (_Float16)hvA.y;                  \
    pk0.z = (_Float16)hvA.z; pk0.w = (_Float16)hvA.w;                  \
    pk1.x = (_Float16)hvB.x; pk1.y = (_Float16)hvB.y;                  \
    pk1.z = (_Float16)hvB.z; pk1.w = (_Float16)hvB.w;                  \
    *(half4*)(hn + wo0) = pk0;                                         \
    *(half4*)(hn + wo1) = pk1;                                         \
    block_sync_lds();                                                  \
  }

__global__ __launch_bounds__(256, 1) void rnn_scan(
    const float* __restrict__ xq, const float* __restrict__ Whh,
    const float* __restrict__ bhh, const float* __restrict__ bh,
    const float* __restrict__ Wfc, const float* __restrict__ bfc,
    float* __restrict__ out) {
  const int tid = threadIdx.x;
  const int w = tid >> 6;            // wave 0..3
  const int lane = tid & 63;
  const int fr = lane & 15;          // batch index this lane carries
  const int fk = lane >> 4;          // k-group / D-row-group
  const int gb = blockIdx.x * 16;    // batch-group base
  const int cb0 = 32 * w;            // tile0 col base
  const int cb1 = 32 * w + 16;       // tile1 col base

  __shared__ __align__(16) char hls[2][16 * 256];  // h f16, 2 x 4 KiB
  __shared__ float hfin[16][RNN_H];                // final h (fp32) for FC

  // A-frags (weights): W_hh[cb+fr][32c+8fk .. +7], 2 tiles x 4 chunks.
  half8 w0c0, w0c1, w0c2, w0c3, w1c0, w1c1, w1c2, w1c3;
  {
    const float* wr0 = &Whh[(size_t)(cb0 + fr) * RNN_H + 8 * fk];
    const float* wr1 = &Whh[(size_t)(cb1 + fr) * RNN_H + 8 * fk];
#define LDW8(dst, base, c)                                        \
    {                                                             \
      const float4 lo = *(const float4*)((base) + 32 * (c));      \
      const float4 hi = *(const float4*)((base) + 32 * (c) + 4);  \
      half8 t;                                                    \
      t[0] = (_Float16)lo.x; t[1] = (_Float16)lo.y;               \
      t[2] = (_Float16)lo.z; t[3] = (_Float16)lo.w;               \
      t[4] = (_Float16)hi.x; t[5] = (_Float16)hi.y;               \
      t[6] = (_Float16)hi.z; t[7] = (_Float16)hi.w;               \
      dst = t;                                                    \
    }
    LDW8(w0c0, wr0, 0) LDW8(w0c1, wr0, 1) LDW8(w0c2, wr0, 2) LDW8(w0c3, wr0, 3)
    LDW8(w1c0, wr1, 0) LDW8(w1c1, wr1, 1) LDW8(w1c2, wr1, 2) LDW8(w1c3, wr1, 3)
  }

  // biases for this lane's 8 output cols (2 tiles x 4 contiguous)
  float4 bias0, bias1;
  {
    const int c0 = cb0 + 4 * fk, c1 = cb1 + 4 * fk;
    const float4 a0 = *(const float4*)&bhh[c0];
    const float4 a1 = *(const float4*)&bhh[c1];
    const float4 b0 = *(const float4*)&bh[c0];
    const float4 b1 = *(const float4*)&bh[c1];
    bias0.x = a0.x + b0.x; bias0.y = a0.y + b0.y;
    bias0.z = a0.z + b0.z; bias0.w = a0.w + b0.w;
    bias1.x = a1.x + b1.x; bias1.y = a1.y + b1.y;
    bias1.z = a1.z + b1.z; bias1.w = a1.w + b1.w;
  }

  // h B-frag read offsets (chunk c): byte = fr*256 + 64c + 16fk, swizzled
  const int swz = (fr & 7) << 4;
  const int rb = fr * 256;
  const int r0 = (rb + 0   + 16 * fk) ^ swz;
  const int r1 = (rb + 64  + 16 * fk) ^ swz;
  const int r2 = (rb + 128 + 16 * fk) ^ swz;
  const int r3 = (rb + 192 + 16 * fk) ^ swz;

  // D write offsets: batch fr, cols cb+4fk..+3 -> one 8-B slot each tile
  const int wo0 = (rb + 2 * (cb0 + 4 * fk)) ^ swz;
  const int wo1 = (rb + 2 * (cb1 + 4 * fk)) ^ swz;

  // zero h buffer 0 (4 KiB, 256 threads x 16 B); zeros are swizzle-invariant
  {
    f32x4 z; z[0] = 0.f; z[1] = 0.f; z[2] = 0.f; z[3] = 0.f;
    ((f32x4*)&hls[0][0])[tid] = z;
  }
  block_sync_lds();

  // xp C-in base pointers: xq[t][gb+fr][cb+4fk], float4 per tile per step
  const float* xb0 = xq + (size_t)(gb + fr) * RNN_H + cb0 + 4 * fk;
  const float* xb1 = xq + (size_t)(gb + fr) * RNN_H + cb1 + 4 * fk;

  float4 pxA0, pxB0, pxA1, pxB1;
  LDPX(pxA0, pxB0, 0)
  LDPX(pxA1, pxB1, 1)

  float4 hvA, hvB;
  hvA.x = hvA.y = hvA.z = hvA.w = 0.f;
  hvB.x = hvB.y = hvB.z = hvB.w = 0.f;

#pragma unroll 1
  for (int t = 0; t < RNN_S; t += 2) {
    const int n0 = (t + 2 < RNN_S) ? t + 2 : RNN_S - 1;
    const int n1 = (t + 3 < RNN_S) ? t + 3 : RNN_S - 1;
    SSTEP(0, 1, pxA0, pxB0, n0)
    SSTEP(1, 0, pxA1, pxB1, n1)
  }
  // final h (fp32, un-quantized): batch fr, cols cb+4fk+reg
  *(float4*)&hfin[fr][cb0 + 4 * fk] = hvA;
  *(float4*)&hfin[fr][cb1 + 4 * fk] = hvB;
  block_sync_lds();

  // FC: 48 threads, one (batch, out) pair each
  if (tid < 16 * RNN_OUT) {
    const int o = tid % RNN_OUT;
    const int bb = tid / RNN_OUT;
    float s = bfc[o];
#pragma unroll 8
    for (int k = 0; k < RNN_H; ++k)
      s = fmaf(Wfc[(size_t)o * RNN_H + k], hfin[bb][k], s);
    out[(gb + bb) * RNN_OUT + o] = s;
  }
}

extern "C" void kernel_launch(void* const* d_in, const int* in_sizes, int n_in,
                              void* d_out, int out_size, void* d_ws, size_t ws_size,
                              hipStream_t stream) {
  const float* x   = (const float*)d_in[0];
  const float* Wxh = (const float*)d_in[1];
  const float* bxh = (const float*)d_in[2];
  const float* Whh = (const float*)d_in[3];
  const float* bhh = (const float*)d_in[4];
  const float* bh  = (const float*)d_in[5];
  const float* Wfc = (const float*)d_in[6];
  const float* bfc = (const float*)d_in[7];
  float* out = (float*)d_out;
  float* xp  = (float*)d_ws;  // 2048*64*128*4 = 64 MiB, layout [t][b][h]

  xproj_mfma<<<dim3((RNN_B * RNN_S) / 128), dim3(256), 0, stream>>>(x, Wxh, bxh, xp);
  rnn_scan<<<dim3(RNN_B / 16), dim3(256), 0, stream>>>(xp, Whh, bhh, bh, Wfc, bfc, out);
}

// Round 7
// 758.879 us; speedup vs baseline: 1.6615x; 1.6615x over previous
//
#include <hip/hip_runtime.h>
#include <hip/hip_bf16.h>
#include <hip/hip_fp16.h>

// SimpleRNN: B=64, S=2048, IN=256, H=128, OUT=3 (all fp32)
// Phase 1: xproj MFMA GEMM (byte-identical to r14/r15; stores xp [t][b][h]).
// Phase 2 (r16): back to the PROVEN r9 dot2 structure (585 us, best ever),
//   with the one structural cut the counters support: 8 waves -> 4 waves
//   (1 wave/SIMD, no intra-SIMD round-robin, half the barrier skew).
//   2 lanes/row, each lane owns a 64-half W_hh slice = 32 half2 VGPRs
//   (r15 demonstrated 32 persistent regs hold; 64+ spills -- r11/r13).
//   1-stage DPP reduce (row pair), plain contiguous h (broadcast reads are
//   conflict-free; 32x b16 contiguous writes are 2-way = free), 4-deep xp
//   prefetch (r15's 2-deep regression lesson), double buffer + 1 LDS-only
//   barrier/step. MFMA-scan experiments (r14/r15) retired: dependent-MFMA
//   chain + redistribution costs exceed the dot2 chain at this tiny size.

#define RNN_B   64
#define RNN_S   2048
#define RNN_IN  256
#define RNN_H   128
#define RNN_OUT 3

typedef _Float16 half2v __attribute__((ext_vector_type(2)));
typedef _Float16 half4 __attribute__((ext_vector_type(4)));
typedef _Float16 half8 __attribute__((ext_vector_type(8)));
typedef float f32x4 __attribute__((ext_vector_type(4)));

#if __has_builtin(__builtin_amdgcn_fdot2)
#define FDOT2(a, b, c) __builtin_amdgcn_fdot2((a), (b), (c), false)
#else
#define FDOT2(a, b, c) \
  fmaf((float)(a).x, (float)(b).x, fmaf((float)(a).y, (float)(b).y, (c)))
#endif

// LDS-only barrier: drains lgkm (LDS) but NOT vmcnt, so global prefetch
// loads stay in flight across the barrier.
__device__ __forceinline__ void block_sync_lds() {
  asm volatile("s_waitcnt lgkmcnt(0)" ::: "memory");
  __builtin_amdgcn_s_barrier();
}

// ---------------------------------------------------------------------------
// Phase 1: f16 MFMA GEMM  C[M=131072, N=128] = A[M,256] * B[128,256]^T + bias
// (byte-identical to rounds 5/6 for attribution; epilogue stores xp[t][b][h])
// ---------------------------------------------------------------------------
#define XLOADC(SET, KC)                                                       \
  {                                                                           \
    const int _kc = (KC);                                                     \
    _Pragma("unroll")                                                         \
    for (int p = 0; p < 4; ++p) {                                             \
      const int row = lr + 32 * p;                                            \
      SET##a[p] = *(const float4*)&x[(size_t)(m0 + row) * RNN_IN + _kc + lc]; \
      SET##b[p] = *(const float4*)&Wxh[(size_t)row * RNN_IN + _kc + lc];      \
    }                                                                         \
  }

#define XSTORE(SET)                                                 \
  {                                                                 \
    _Pragma("unroll")                                               \
    for (int p = 0; p < 4; ++p) {                                   \
      const int row = lr + 32 * p;                                  \
      half4 ha, hb;                                                 \
      ha.x = (_Float16)SET##a[p].x; ha.y = (_Float16)SET##a[p].y;   \
      ha.z = (_Float16)SET##a[p].z; ha.w = (_Float16)SET##a[p].w;   \
      hb.x = (_Float16)SET##b[p].x; hb.y = (_Float16)SET##b[p].y;   \
      hb.z = (_Float16)SET##b[p].z; hb.w = (_Float16)SET##b[p].w;   \
      *(half4*)&Ash[row][lc] = ha;                                  \
      *(half4*)&Bsh[row][lc] = hb;                                  \
    }                                                               \
  }

#define XCOMPUTE()                                                  \
  {                                                                 \
    half8 af[4], bf[4];                                             \
    _Pragma("unroll")                                               \
    for (int m = 0; m < 4; ++m)                                     \
      af[m] = *(const half8*)&Ash[wr * 64 + m * 16 + fr][fk * 8];   \
    _Pragma("unroll")                                               \
    for (int n = 0; n < 4; ++n)                                     \
      bf[n] = *(const half8*)&Bsh[wc * 64 + n * 16 + fr][fk * 8];   \
    _Pragma("unroll")                                               \
    for (int m = 0; m < 4; ++m)                                     \
      _Pragma("unroll")                                             \
      for (int n = 0; n < 4; ++n)                                   \
        acc[m][n] = __builtin_amdgcn_mfma_f32_16x16x32_f16(         \
            af[m], bf[n], acc[m][n], 0, 0, 0);                      \
  }

__global__ __launch_bounds__(256, 2) void xproj_mfma(
    const float* __restrict__ x, const float* __restrict__ Wxh,
    const float* __restrict__ bxh, float* __restrict__ xp) {
  __shared__ __align__(16) _Float16 Ash[128][40];
  __shared__ __align__(16) _Float16 Bsh[128][40];

  const int tid = threadIdx.x;
  const int m0 = blockIdx.x * 128;
  const int wv = tid >> 6;
  const int lane = tid & 63;
  const int wr = wv >> 1;
  const int wc = wv & 1;
  const int fr = lane & 15;
  const int fk = lane >> 4;

  const int lr = tid >> 3;
  const int lc = (tid & 7) * 4;

  f32x4 acc[4][4];
#pragma unroll
  for (int m = 0; m < 4; ++m)
#pragma unroll
    for (int n = 0; n < 4; ++n) {
      acc[m][n][0] = 0.f; acc[m][n][1] = 0.f;
      acc[m][n][2] = 0.f; acc[m][n][3] = 0.f;
    }

  float4 Aa[4], Ab[4], Ba[4], Bb[4];
  XLOADC(A, 0)

#pragma unroll 1
  for (int kc = 0; kc < RNN_IN; kc += 64) {
    XSTORE(A)
    { const int nk = kc + 32; XLOADC(B, nk < RNN_IN ? nk : RNN_IN - 32) }
    block_sync_lds();
    XCOMPUTE()
    block_sync_lds();
    XSTORE(B)
    { const int nk = kc + 64; XLOADC(A, nk < RNN_IN ? nk : RNN_IN - 32) }
    block_sync_lds();
    XCOMPUTE()
    block_sync_lds();
  }

  float bb[4];
#pragma unroll
  for (int n = 0; n < 4; ++n) bb[n] = bxh[wc * 64 + n * 16 + fr];
#pragma unroll
  for (int m = 0; m < 4; ++m) {
    const size_t rbase = (size_t)(m0 + wr * 64 + m * 16 + 4 * fk);
#pragma unroll
    for (int reg = 0; reg < 4; ++reg) {
      const size_t grow = rbase + reg;            // global row = b*2048 + t
      const size_t bidx = grow >> 11;             // batch
      const size_t tidx = grow & 2047;            // timestep
      float* rowp = &xp[(tidx * RNN_B + bidx) * RNN_H];
#pragma unroll
      for (int n = 0; n < 4; ++n)
        rowp[wc * 64 + n * 16 + fr] = acc[m][n][reg] + bb[n];
    }
  }
}

// fast tanh: 1 - 2/(exp(2x)+1); saturates correctly at +-inf
__device__ __forceinline__ float fast_tanh(float a) {
  const float e = __expf(2.f * a);
  return 1.f - 2.f / (e + 1.f);
}

// ---------------------------------------------------------------------------
// Phase 2: recurrence. grid=64 (one per batch), block=256 (4 waves, 1/SIMD).
// Thread (row r = 32*wv + lane>>1, slice hh = lane&1) owns
// W_hh[r][64*hh .. 64*hh+63] as 32 named half2 VGPRs.
// h (128 f16 = 256 B) double-buffered, plainly contiguous:
//   reads: each lane 8x ds_read_b128 of its 128-B slice -- only 2 distinct
//   addresses per instr across the wave (broadcast + 2-way = free);
//   writes: 32 lanes (hh==0) write b16 at consecutive rows = 2-way, free.
// Row-pair reduce = ONE DPP xor1. One LDS-only barrier per step.
// ---------------------------------------------------------------------------
union U8 { half8 v; float f[4]; };

#define WDECL(i) half2v w##i;
#define W_ALL(M) \
  M(0)  M(1)  M(2)  M(3)  M(4)  M(5)  M(6)  M(7)  \
  M(8)  M(9)  M(10) M(11) M(12) M(13) M(14) M(15) \
  M(16) M(17) M(18) M(19) M(20) M(21) M(22) M(23) \
  M(24) M(25) M(26) M(27) M(28) M(29) M(30) M(31)

// load one float4 (idx) -> two half2 regs
#define WLOAD2(i0, i1, idx)                                   \
  {                                                           \
    const float4 f = wrow4[idx];                              \
    half2v t; t.x = (_Float16)f.x; t.y = (_Float16)f.y;       \
    w##i0 = t;                                                \
    half2v s; s.x = (_Float16)f.z; s.y = (_Float16)f.w;       \
    w##i1 = s;                                                \
  }
#define W_PAIRS(M) \
  M(0,1,0)    M(2,3,1)    M(4,5,2)    M(6,7,3)    \
  M(8,9,4)    M(10,11,5)  M(12,13,6)  M(14,15,7)  \
  M(16,17,8)  M(18,19,9)  M(20,21,10) M(22,23,11) \
  M(24,25,12) M(26,27,13) M(28,29,14) M(30,31,15)

// one 16-B h-chunk against 4 weight regs, 4 independent acc chains
#define D4(U, wa, wb, wc_, wd)                                   \
  a0 = FDOT2(wa,  __builtin_bit_cast(half2v, (U).f[0]), a0);     \
  a1 = FDOT2(wb,  __builtin_bit_cast(half2v, (U).f[1]), a1);     \
  a2 = FDOT2(wc_, __builtin_bit_cast(half2v, (U).f[2]), a2);     \
  a3 = FDOT2(wd,  __builtin_bit_cast(half2v, (U).f[3]), a3);

#define SSTEP(CUR, NXT, PX, TNEXT)                                    \
  {                                                                   \
    const float xin = PX;                                             \
    PX = xpb[(size_t)(TNEXT) * (RNN_B * RNN_H)];                      \
    const half8* hp = (const half8*)&hs[CUR][64 * hh];                \
    U8 u0, u1, u2, u3;                                                \
    u0.v = hp[0]; u1.v = hp[1]; u2.v = hp[2]; u3.v = hp[3];           \
    float a0 = 0.f, a1 = 0.f, a2 = 0.f, a3 = 0.f;                     \
    D4(u0, w0,  w1,  w2,  w3)                                         \
    D4(u1, w4,  w5,  w6,  w7)                                         \
    D4(u2, w8,  w9,  w10, w11)                                        \
    D4(u3, w12, w13, w14, w15)                                        \
    U8 u4, u5, u6, u7;                                                \
    u4.v = hp[4]; u5.v = hp[5]; u6.v = hp[6]; u7.v = hp[7];           \
    D4(u4, w16, w17, w18, w19)                                        \
    D4(u5, w20, w21, w22, w23)                                        \
    D4(u6, w24, w25, w26, w27)                                        \
    D4(u7, w28, w29, w30, w31)                                        \
    float s = (a0 + a1) + (a2 + a3);                                  \
    {                                                                 \
      int tdpp = __builtin_amdgcn_mov_dpp(                            \
          __builtin_bit_cast(int, s), 0xB1, 0xF, 0xF, true);          \
      s += __builtin_bit_cast(float, tdpp);                           \
    }                                                                 \
    const float hv = fast_tanh(bias + xin + s);                       \
    if (hh == 0) hs[NXT][r] = (_Float16)hv;                           \
    hvF = hv;                                                         \
    block_sync_lds();                                                 \
  }

__global__ __launch_bounds__(256, 1) void rnn_scan(
    const float* __restrict__ xq, const float* __restrict__ Whh,
    const float* __restrict__ bhh, const float* __restrict__ bh,
    const float* __restrict__ Wfc, const float* __restrict__ bfc,
    float* __restrict__ out) {
  const int b = blockIdx.x;
  const int tid = threadIdx.x;        // 0..255
  const int wv = tid >> 6;            // wave 0..3
  const int lane = tid & 63;
  const int r = 32 * wv + (lane >> 1);  // row 0..127
  const int hh = lane & 1;              // 64-half slice 0/1

  __shared__ __align__(16) _Float16 hs[2][RNN_H];  // 2 x 256 B
  __shared__ float hfin[RNN_H];                    // final h (fp32) for FC

  const float4* wrow4 = (const float4*)&Whh[(size_t)r * RNN_H + 64 * hh];
  W_ALL(WDECL)
  W_PAIRS(WLOAD2)

  const float bias = bhh[r] + bh[r];

  // zero h buffer 0
  if (tid < RNN_H) hs[0][tid] = (_Float16)0.f;
  block_sync_lds();

  // xp layout [t][b][h]: element (t, b, r) at t*B*H + b*H + r
  const float* xpb = xq + (size_t)b * RNN_H + r;

  // 4-deep fp32 prefetch (lane pairs duplicate the same address -- coalesced)
  float p0 = xpb[(size_t)0 * (RNN_B * RNN_H)];
  float p1 = xpb[(size_t)1 * (RNN_B * RNN_H)];
  float p2 = xpb[(size_t)2 * (RNN_B * RNN_H)];
  float p3 = xpb[(size_t)3 * (RNN_B * RNN_H)];

  float hvF = 0.f;

#pragma unroll 1
  for (int t = 0; t < RNN_S; t += 4) {
    const int n0 = (t + 4 < RNN_S) ? t + 4 : RNN_S - 1;
    const int n1 = (t + 5 < RNN_S) ? t + 5 : RNN_S - 1;
    const int n2 = (t + 6 < RNN_S) ? t + 6 : RNN_S - 1;
    const int n3 = (t + 7 < RNN_S) ? t + 7 : RNN_S - 1;
    SSTEP(0, 1, p0, n0)
    SSTEP(1, 0, p1, n1)
    SSTEP(0, 1, p2, n2)
    SSTEP(1, 0, p3, n3)
  }
  // final h (fp32, un-quantized) for row r is in hvF (both lanes of the pair)

  if (hh == 0) hfin[r] = hvF;
  block_sync_lds();

  // fused FC: 3 threads, one output each (128 fma, runs once -- negligible)
  if (tid < RNN_OUT) {
    float s = bfc[tid];
#pragma unroll 8
    for (int k = 0; k < RNN_H; ++k)
      s = fmaf(Wfc[(size_t)tid * RNN_H + k], hfin[k], s);
    out[b * RNN_OUT + tid] = s;
  }
}

extern "C" void kernel_launch(void* const* d_in, const int* in_sizes, int n_in,
                              void* d_out, int out_size, void* d_ws, size_t ws_size,
                              hipStream_t stream) {
  const float* x   = (const float*)d_in[0];
  const float* Wxh = (const float*)d_in[1];
  const float* bxh = (const float*)d_in[2];
  const float* Whh = (const float*)d_in[3];
  const float* bhh = (const float*)d_in[4];
  const float* bh  = (const float*)d_in[5];
  const float* Wfc = (const float*)d_in[6];
  const float* bfc = (const float*)d_in[7];
  float* out = (float*)d_out;
  float* xp  = (float*)d_ws;  // 2048*64*128*4 = 64 MiB, layout [t][b][h]

  xproj_mfma<<<dim3((RNN_B * RNN_S) / 128), dim3(256), 0, stream>>>(x, Wxh, bxh, xp);
  rnn_scan<<<dim3(RNN_B), dim3(256), 0, stream>>>(xp, Whh, bhh, bh, Wfc, bfc, out);
}

// Round 8
// 707.193 us; speedup vs baseline: 1.7830x; 1.0731x over previous
//
#include <hip/hip_runtime.h>
#include <hip/hip_bf16.h>
#include <hip/hip_fp16.h>

// SimpleRNN: B=64, S=2048, IN=256, H=128, OUT=3 (all fp32)
// Phase 1: xproj MFMA GEMM (byte-identical to r16; stores xp [t][b][h]).
// Phase 2 (r17): r16's 4-wave dot2 scan (554 us, best) with three serial-
//   chain cuts, everything else identical:
//   1. tanh tail via v_rcp_f32: "2.f/(e+1.f)" compiles to the IEEE divide
//      sequence (~10 ops, ~40 cyc) without fast-math -- ON THE CHAIN every
//      step. fmaf(-2, rcp(e+1), 1) is 2 ops; saturates correctly at +-inf.
//   2. unconditional h write: after the DPP pair-exchange BOTH lanes hold
//      the identical hv -> same value to same address; drop the exec-mask
//      branch (~4 instr on the chain).
//   3. issue all 8 ds_read_b128 before the xp refill load.

#define RNN_B   64
#define RNN_S   2048
#define RNN_IN  256
#define RNN_H   128
#define RNN_OUT 3

typedef _Float16 half2v __attribute__((ext_vector_type(2)));
typedef _Float16 half4 __attribute__((ext_vector_type(4)));
typedef _Float16 half8 __attribute__((ext_vector_type(8)));
typedef float f32x4 __attribute__((ext_vector_type(4)));

#if __has_builtin(__builtin_amdgcn_fdot2)
#define FDOT2(a, b, c) __builtin_amdgcn_fdot2((a), (b), (c), false)
#else
#define FDOT2(a, b, c) \
  fmaf((float)(a).x, (float)(b).x, fmaf((float)(a).y, (float)(b).y, (c)))
#endif

// LDS-only barrier: drains lgkm (LDS) but NOT vmcnt, so global prefetch
// loads stay in flight across the barrier.
__device__ __forceinline__ void block_sync_lds() {
  asm volatile("s_waitcnt lgkmcnt(0)" ::: "memory");
  __builtin_amdgcn_s_barrier();
}

// ---------------------------------------------------------------------------
// Phase 1: f16 MFMA GEMM  C[M=131072, N=128] = A[M,256] * B[128,256]^T + bias
// (byte-identical to rounds 5-7 for attribution; epilogue stores xp[t][b][h])
// ---------------------------------------------------------------------------
#define XLOADC(SET, KC)                                                       \
  {                                                                           \
    const int _kc = (KC);                                                     \
    _Pragma("unroll")                                                         \
    for (int p = 0; p < 4; ++p) {                                             \
      const int row = lr + 32 * p;                                            \
      SET##a[p] = *(const float4*)&x[(size_t)(m0 + row) * RNN_IN + _kc + lc]; \
      SET##b[p] = *(const float4*)&Wxh[(size_t)row * RNN_IN + _kc + lc];      \
    }                                                                         \
  }

#define XSTORE(SET)                                                 \
  {                                                                 \
    _Pragma("unroll")                                               \
    for (int p = 0; p < 4; ++p) {                                   \
      const int row = lr + 32 * p;                                  \
      half4 ha, hb;                                                 \
      ha.x = (_Float16)SET##a[p].x; ha.y = (_Float16)SET##a[p].y;   \
      ha.z = (_Float16)SET##a[p].z; ha.w = (_Float16)SET##a[p].w;   \
      hb.x = (_Float16)SET##b[p].x; hb.y = (_Float16)SET##b[p].y;   \
      hb.z = (_Float16)SET##b[p].z; hb.w = (_Float16)SET##b[p].w;   \
      *(half4*)&Ash[row][lc] = ha;                                  \
      *(half4*)&Bsh[row][lc] = hb;                                  \
    }                                                               \
  }

#define XCOMPUTE()                                                  \
  {                                                                 \
    half8 af[4], bf[4];                                             \
    _Pragma("unroll")                                               \
    for (int m = 0; m < 4; ++m)                                     \
      af[m] = *(const half8*)&Ash[wr * 64 + m * 16 + fr][fk * 8];   \
    _Pragma("unroll")                                               \
    for (int n = 0; n < 4; ++n)                                     \
      bf[n] = *(const half8*)&Bsh[wc * 64 + n * 16 + fr][fk * 8];   \
    _Pragma("unroll")                                               \
    for (int m = 0; m < 4; ++m)                                     \
      _Pragma("unroll")                                             \
      for (int n = 0; n < 4; ++n)                                   \
        acc[m][n] = __builtin_amdgcn_mfma_f32_16x16x32_f16(         \
            af[m], bf[n], acc[m][n], 0, 0, 0);                      \
  }

__global__ __launch_bounds__(256, 2) void xproj_mfma(
    const float* __restrict__ x, const float* __restrict__ Wxh,
    const float* __restrict__ bxh, float* __restrict__ xp) {
  __shared__ __align__(16) _Float16 Ash[128][40];
  __shared__ __align__(16) _Float16 Bsh[128][40];

  const int tid = threadIdx.x;
  const int m0 = blockIdx.x * 128;
  const int wv = tid >> 6;
  const int lane = tid & 63;
  const int wr = wv >> 1;
  const int wc = wv & 1;
  const int fr = lane & 15;
  const int fk = lane >> 4;

  const int lr = tid >> 3;
  const int lc = (tid & 7) * 4;

  f32x4 acc[4][4];
#pragma unroll
  for (int m = 0; m < 4; ++m)
#pragma unroll
    for (int n = 0; n < 4; ++n) {
      acc[m][n][0] = 0.f; acc[m][n][1] = 0.f;
      acc[m][n][2] = 0.f; acc[m][n][3] = 0.f;
    }

  float4 Aa[4], Ab[4], Ba[4], Bb[4];
  XLOADC(A, 0)

#pragma unroll 1
  for (int kc = 0; kc < RNN_IN; kc += 64) {
    XSTORE(A)
    { const int nk = kc + 32; XLOADC(B, nk < RNN_IN ? nk : RNN_IN - 32) }
    block_sync_lds();
    XCOMPUTE()
    block_sync_lds();
    XSTORE(B)
    { const int nk = kc + 64; XLOADC(A, nk < RNN_IN ? nk : RNN_IN - 32) }
    block_sync_lds();
    XCOMPUTE()
    block_sync_lds();
  }

  float bb[4];
#pragma unroll
  for (int n = 0; n < 4; ++n) bb[n] = bxh[wc * 64 + n * 16 + fr];
#pragma unroll
  for (int m = 0; m < 4; ++m) {
    const size_t rbase = (size_t)(m0 + wr * 64 + m * 16 + 4 * fk);
#pragma unroll
    for (int reg = 0; reg < 4; ++reg) {
      const size_t grow = rbase + reg;            // global row = b*2048 + t
      const size_t bidx = grow >> 11;             // batch
      const size_t tidx = grow & 2047;            // timestep
      float* rowp = &xp[(tidx * RNN_B + bidx) * RNN_H];
#pragma unroll
      for (int n = 0; n < 4; ++n)
        rowp[wc * 64 + n * 16 + fr] = acc[m][n][reg] + bb[n];
    }
  }
}

// fast tanh: 1 - 2/(exp(2x)+1) with raw v_rcp_f32 (NOT the IEEE divide
// sequence the compiler emits for "/" without fast-math).
// a=+inf: e=inf, rcp=0 -> 1.  a=-inf: e=0, rcp(1)=1 -> -1.  Correct.
__device__ __forceinline__ float fast_tanh(float a) {
  const float e = __expf(2.f * a);
  return fmaf(-2.f, __builtin_amdgcn_rcpf(e + 1.f), 1.f);
}

// ---------------------------------------------------------------------------
// Phase 2: recurrence. grid=64 (one per batch), block=256 (4 waves, 1/SIMD).
// Thread (row r = 32*wv + lane>>1, slice hh = lane&1) owns
// W_hh[r][64*hh .. 64*hh+63] as 32 named half2 VGPRs.
// ---------------------------------------------------------------------------
union U8 { half8 v; float f[4]; };

#define WDECL(i) half2v w##i;
#define W_ALL(M) \
  M(0)  M(1)  M(2)  M(3)  M(4)  M(5)  M(6)  M(7)  \
  M(8)  M(9)  M(10) M(11) M(12) M(13) M(14) M(15) \
  M(16) M(17) M(18) M(19) M(20) M(21) M(22) M(23) \
  M(24) M(25) M(26) M(27) M(28) M(29) M(30) M(31)

#define WLOAD2(i0, i1, idx)                                   \
  {                                                           \
    const float4 f = wrow4[idx];                              \
    half2v t; t.x = (_Float16)f.x; t.y = (_Float16)f.y;       \
    w##i0 = t;                                                \
    half2v s; s.x = (_Float16)f.z; s.y = (_Float16)f.w;       \
    w##i1 = s;                                                \
  }
#define W_PAIRS(M) \
  M(0,1,0)    M(2,3,1)    M(4,5,2)    M(6,7,3)    \
  M(8,9,4)    M(10,11,5)  M(12,13,6)  M(14,15,7)  \
  M(16,17,8)  M(18,19,9)  M(20,21,10) M(22,23,11) \
  M(24,25,12) M(26,27,13) M(28,29,14) M(30,31,15)

#define D4(U, wa, wb, wc_, wd)                                   \
  a0 = FDOT2(wa,  __builtin_bit_cast(half2v, (U).f[0]), a0);     \
  a1 = FDOT2(wb,  __builtin_bit_cast(half2v, (U).f[1]), a1);     \
  a2 = FDOT2(wc_, __builtin_bit_cast(half2v, (U).f[2]), a2);     \
  a3 = FDOT2(wd,  __builtin_bit_cast(half2v, (U).f[3]), a3);

#define SSTEP(CUR, NXT, PX, TNEXT)                                    \
  {                                                                   \
    const half8* hp = (const half8*)&hs[CUR][64 * hh];                \
    U8 u0, u1, u2, u3, u4, u5, u6, u7;                                \
    u0.v = hp[0]; u1.v = hp[1]; u2.v = hp[2]; u3.v = hp[3];           \
    u4.v = hp[4]; u5.v = hp[5]; u6.v = hp[6]; u7.v = hp[7];           \
    const float xin = PX;                                             \
    PX = xpb[(size_t)(TNEXT) * (RNN_B * RNN_H)];                      \
    float a0 = 0.f, a1 = 0.f, a2 = 0.f, a3 = 0.f;                     \
    D4(u0, w0,  w1,  w2,  w3)                                         \
    D4(u1, w4,  w5,  w6,  w7)                                         \
    D4(u2, w8,  w9,  w10, w11)                                        \
    D4(u3, w12, w13, w14, w15)                                        \
    D4(u4, w16, w17, w18, w19)                                        \
    D4(u5, w20, w21, w22, w23)                                        \
    D4(u6, w24, w25, w26, w27)                                        \
    D4(u7, w28, w29, w30, w31)                                        \
    float s = (a0 + a1) + (a2 + a3);                                  \
    {                                                                 \
      int tdpp = __builtin_amdgcn_mov_dpp(                            \
          __builtin_bit_cast(int, s), 0xB1, 0xF, 0xF, true);          \
      s += __builtin_bit_cast(float, tdpp);                           \
    }                                                                 \
    const float hv = fast_tanh(bias + xin + s);                       \
    hs[NXT][r] = (_Float16)hv;   /* both pair-lanes: same value */    \
    hvF = hv;                                                         \
    block_sync_lds();                                                 \
  }

__global__ __launch_bounds__(256, 1) void rnn_scan(
    const float* __restrict__ xq, const float* __restrict__ Whh,
    const float* __restrict__ bhh, const float* __restrict__ bh,
    const float* __restrict__ Wfc, const float* __restrict__ bfc,
    float* __restrict__ out) {
  const int b = blockIdx.x;
  const int tid = threadIdx.x;        // 0..255
  const int wv = tid >> 6;            // wave 0..3
  const int lane = tid & 63;
  const int r = 32 * wv + (lane >> 1);  // row 0..127
  const int hh = lane & 1;              // 64-half slice 0/1

  __shared__ __align__(16) _Float16 hs[2][RNN_H];  // 2 x 256 B
  __shared__ float hfin[RNN_H];                    // final h (fp32) for FC

  const float4* wrow4 = (const float4*)&Whh[(size_t)r * RNN_H + 64 * hh];
  W_ALL(WDECL)
  W_PAIRS(WLOAD2)

  const float bias = bhh[r] + bh[r];

  // zero h buffer 0
  if (tid < RNN_H) hs[0][tid] = (_Float16)0.f;
  block_sync_lds();

  // xp layout [t][b][h]: element (t, b, r) at t*B*H + b*H + r
  const float* xpb = xq + (size_t)b * RNN_H + r;

  // 4-deep fp32 prefetch (lane pairs duplicate the same address -- coalesced)
  float p0 = xpb[(size_t)0 * (RNN_B * RNN_H)];
  float p1 = xpb[(size_t)1 * (RNN_B * RNN_H)];
  float p2 = xpb[(size_t)2 * (RNN_B * RNN_H)];
  float p3 = xpb[(size_t)3 * (RNN_B * RNN_H)];

  float hvF = 0.f;

#pragma unroll 1
  for (int t = 0; t < RNN_S; t += 4) {
    const int n0 = (t + 4 < RNN_S) ? t + 4 : RNN_S - 1;
    const int n1 = (t + 5 < RNN_S) ? t + 5 : RNN_S - 1;
    const int n2 = (t + 6 < RNN_S) ? t + 6 : RNN_S - 1;
    const int n3 = (t + 7 < RNN_S) ? t + 7 : RNN_S - 1;
    SSTEP(0, 1, p0, n0)
    SSTEP(1, 0, p1, n1)
    SSTEP(0, 1, p2, n2)
    SSTEP(1, 0, p3, n3)
  }

  hfin[r] = hvF;  // both pair-lanes write the same value
  block_sync_lds();

  // fused FC: 3 threads, one output each (runs once -- negligible)
  if (tid < RNN_OUT) {
    float s = bfc[tid];
#pragma unroll 8
    for (int k = 0; k < RNN_H; ++k)
      s = fmaf(Wfc[(size_t)tid * RNN_H + k], hfin[k], s);
    out[b * RNN_OUT + tid] = s;
  }
}

extern "C" void kernel_launch(void* const* d_in, const int* in_sizes, int n_in,
                              void* d_out, int out_size, void* d_ws, size_t ws_size,
                              hipStream_t stream) {
  const float* x   = (const float*)d_in[0];
  const float* Wxh = (const float*)d_in[1];
  const float* bxh = (const float*)d_in[2];
  const float* Whh = (const float*)d_in[3];
  const float* bhh = (const float*)d_in[4];
  const float* bh  = (const float*)d_in[5];
  const float* Wfc = (const float*)d_in[6];
  const float* bfc = (const float*)d_in[7];
  float* out = (float*)d_out;
  float* xp  = (float*)d_ws;  // 2048*64*128*4 = 64 MiB, layout [t][b][h]

  xproj_mfma<<<dim3((RNN_B * RNN_S) / 128), dim3(256), 0, stream>>>(x, Wxh, bxh, xp);
  rnn_scan<<<dim3(RNN_B), dim3(256), 0, stream>>>(xp, Whh, bhh, bh, Wfc, bfc, out);
}